// Round 1
// baseline (891.907 us; speedup 1.0000x reference)
//
#include <hip/hip_runtime.h>
#include <math.h>

// ---------------------------------------------------------------------------
// SymmetricalResidualGAT: EdgeConv(max) + GAT x4 (H=2, C=128) + linears, fp32.
// N=20000, E=320000, F=128, HID=128, OC=256.
// ---------------------------------------------------------------------------

#define NEG_SLOPE 0.2f

__device__ __forceinline__ float leaky(float x) { return x > 0.f ? x : NEG_SLOPE * x; }

__device__ __forceinline__ void atomicMaxF(float* addr, float v) {
  // monotone-in-float-order trick; addr pre-initialized to -inf (0xFF800000)
  if (v >= 0.f) atomicMax((int*)addr, __float_as_int(v));
  else          atomicMin((unsigned int*)addr, __float_as_uint(v));
}

// ---------------- utility kernels ----------------
__global__ __launch_bounds__(256) void k_zero_int(int* p, int n) {
  int i = blockIdx.x * 256 + threadIdx.x;
  if (i < n) p[i] = 0;
}

__global__ __launch_bounds__(256) void k_fill_f32(float* p, float v, int n) {
  int i = blockIdx.x * 256 + threadIdx.x;
  if (i < n) p[i] = v;
}

__global__ __launch_bounds__(256) void k_hist(const int* __restrict__ ei, int* __restrict__ deg,
                                              int E) {
  int e = blockIdx.x * 256 + threadIdx.x;
  if (e < E) atomicAdd(&deg[ei[E + e]], 1);
}

__global__ __launch_bounds__(1024) void k_scan(const int* __restrict__ deg, int* __restrict__ rs,
                                               int n) {
  __shared__ int buf[1024];
  __shared__ int carry_s;
  int tid = threadIdx.x;
  if (tid == 0) carry_s = 0;
  __syncthreads();
  for (int base = 0; base < n; base += 1024) {
    int i = base + tid;
    int v = (i < n) ? deg[i] : 0;
    buf[tid] = v;
    __syncthreads();
    for (int off = 1; off < 1024; off <<= 1) {
      int t = (tid >= off) ? buf[tid - off] : 0;
      __syncthreads();
      buf[tid] += t;
      __syncthreads();
    }
    int carry = carry_s;
    if (i < n) rs[i] = carry + buf[tid] - v;  // exclusive
    __syncthreads();
    if (tid == 1023) carry_s = carry + buf[1023];
    __syncthreads();
  }
  if (tid == 0) rs[n] = carry_s;
}

__global__ __launch_bounds__(256) void k_scatter(const int* __restrict__ ei,
                                                 const int* __restrict__ rs,
                                                 int* __restrict__ cnt,
                                                 int* __restrict__ csr_src,
                                                 int* __restrict__ csr_dst, int E) {
  int e = blockIdx.x * 256 + threadIdx.x;
  if (e < E) {
    int d = ei[E + e];
    int p = atomicAdd(&cnt[d], 1);
    int slot = rs[d] + p;
    csr_src[slot] = ei[e];
    csr_dst[slot] = d;
  }
}

// Build combined EdgeConv layer-1 weight: [u | v] = x @ Bcat + bias_cat
// Bcat[k][j] = j<128 ? W1top[k][j]-W1bot[k][j] : W1bot[k][j-128]
__global__ __launch_bounds__(256) void k_prep(const float* __restrict__ w1,
                                              const float* __restrict__ b1,
                                              float* __restrict__ Bcat,
                                              float* __restrict__ bias_cat) {
  int idx = blockIdx.x * 256 + threadIdx.x;  // 0..32767
  int k = idx >> 8;
  int j = idx & 255;
  float v;
  if (j < 128) v = w1[k * 128 + j] - w1[(k + 128) * 128 + j];
  else         v = w1[(k + 128) * 128 + (j - 128)];
  Bcat[idx] = v;
  if (idx < 256) bias_cat[idx] = (idx < 128) ? b1[idx] : 0.f;
}

// ---------------- generic fp32 tiled GEMM: C = A[MxK] @ B[KxN] (+bias) ----------------
#define GBM 128
#define GBN 64
#define GBK 16
__global__ __launch_bounds__(256) void k_gemm(const float* __restrict__ A,
                                              const float* __restrict__ B,
                                              const float* __restrict__ bias,
                                              float* __restrict__ C, int M, int K, int Nc) {
  __shared__ float As[GBK][GBM + 4];
  __shared__ float Bs[GBK][GBN + 4];
  const int tid = threadIdx.x;
  const int bm = blockIdx.x * GBM;
  const int bn = blockIdx.y * GBN;
  const int ty = tid >> 4;  // 0..15 -> 8 rows each
  const int tx = tid & 15;  // 0..15 -> 4 cols each
  float acc[8][4] = {};
  for (int k0 = 0; k0 < K; k0 += GBK) {
    #pragma unroll
    for (int s = tid; s < (GBM * GBK / 4); s += 256) {
      int r = s >> 2;
      int q = (s & 3) << 2;
      float4 v = make_float4(0.f, 0.f, 0.f, 0.f);
      int gr = bm + r;
      if (gr < M) v = *(const float4*)&A[(size_t)gr * K + k0 + q];
      As[q + 0][r] = v.x; As[q + 1][r] = v.y; As[q + 2][r] = v.z; As[q + 3][r] = v.w;
    }
    {
      int r = tid >> 4;
      int q = (tid & 15) << 2;
      float4 v = *(const float4*)&B[(size_t)(k0 + r) * Nc + bn + q];
      *(float4*)&Bs[r][q] = v;
    }
    __syncthreads();
    #pragma unroll
    for (int kk = 0; kk < GBK; ++kk) {
      float4 b4 = *(float4*)&Bs[kk][tx << 2];
      float4 a0 = *(float4*)&As[kk][ty << 3];
      float4 a1 = *(float4*)&As[kk][(ty << 3) + 4];
      float am[8] = {a0.x, a0.y, a0.z, a0.w, a1.x, a1.y, a1.z, a1.w};
      #pragma unroll
      for (int i = 0; i < 8; ++i) {
        acc[i][0] += am[i] * b4.x;
        acc[i][1] += am[i] * b4.y;
        acc[i][2] += am[i] * b4.z;
        acc[i][3] += am[i] * b4.w;
      }
    }
    __syncthreads();
  }
  float4 bv = make_float4(0.f, 0.f, 0.f, 0.f);
  if (bias) bv = *(const float4*)&bias[bn + (tx << 2)];
  #pragma unroll
  for (int i = 0; i < 8; ++i) {
    int gr = bm + (ty << 3) + i;
    if (gr < M) {
      float4 o;
      o.x = acc[i][0] + bv.x;
      o.y = acc[i][1] + bv.y;
      o.z = acc[i][2] + bv.z;
      o.w = acc[i][3] + bv.w;
      *(float4*)&C[(size_t)gr * Nc + bn + (tx << 2)] = o;
    }
  }
}

// ---------------- EdgeConv layer-2 + segment-max, fused over sorted edges ----------------
// per block: 64 sorted edges x 128 channels. P = relu(u[dst]+v[src]); H2 = P@W2 + b2;
// then run-wise max + atomicMaxF into x0 (pre-filled with -inf).
__global__ __launch_bounds__(256) void k_edgeconv(const float* __restrict__ uv,
                                                  const int* __restrict__ csr_src,
                                                  const int* __restrict__ csr_dst,
                                                  const float* __restrict__ w2,
                                                  const float* __restrict__ b2,
                                                  float* __restrict__ x0, int E) {
  __shared__ float P[64][128];
  __shared__ float W2s[16][132];
  __shared__ int sSrc[64], sDst[64];
  int tid = threadIdx.x;
  int e0 = blockIdx.x * 64;
  if (tid < 64) {
    int e = e0 + tid;
    sSrc[tid] = (e < E) ? csr_src[e] : -1;
    sDst[tid] = (e < E) ? csr_dst[e] : -1;
  }
  __syncthreads();
  for (int s = tid; s < 64 * 32; s += 256) {
    int r = s >> 5;
    int q = (s & 31) << 2;
    float4 pv = make_float4(0.f, 0.f, 0.f, 0.f);
    int sn = sSrc[r], dn = sDst[r];
    if (sn >= 0) {
      float4 u4 = *(const float4*)&uv[(size_t)dn * 256 + q];
      float4 v4 = *(const float4*)&uv[(size_t)sn * 256 + 128 + q];
      pv.x = fmaxf(u4.x + v4.x, 0.f);
      pv.y = fmaxf(u4.y + v4.y, 0.f);
      pv.z = fmaxf(u4.z + v4.z, 0.f);
      pv.w = fmaxf(u4.w + v4.w, 0.f);
    }
    *(float4*)&P[r][q] = pv;
  }
  int ty = tid >> 5;  // 0..7 -> 8 edges each
  int tx = tid & 31;  // 0..31 -> 4 channels each
  float acc[8][4] = {};
  for (int k0 = 0; k0 < 128; k0 += 16) {
    __syncthreads();
    for (int s = tid; s < 512; s += 256) {
      int kr = s >> 5;
      int q = (s & 31) << 2;
      *(float4*)&W2s[kr][q] = *(const float4*)&w2[(size_t)(k0 + kr) * 128 + q];
    }
    __syncthreads();
    #pragma unroll
    for (int kk = 0; kk < 16; ++kk) {
      float4 b4 = *(float4*)&W2s[kk][tx << 2];
      #pragma unroll
      for (int i = 0; i < 8; ++i) {
        float a = P[ty * 8 + i][k0 + kk];
        acc[i][0] += a * b4.x;
        acc[i][1] += a * b4.y;
        acc[i][2] += a * b4.z;
        acc[i][3] += a * b4.w;
      }
    }
  }
  float4 bb = *(const float4*)&b2[tx << 2];
  float rv0 = acc[0][0] + bb.x, rv1 = acc[0][1] + bb.y, rv2 = acc[0][2] + bb.z,
        rv3 = acc[0][3] + bb.w;
  int rd = sDst[ty * 8];
  #pragma unroll
  for (int i = 1; i < 8; ++i) {
    int d = sDst[ty * 8 + i];
    float c0 = acc[i][0] + bb.x, c1 = acc[i][1] + bb.y, c2 = acc[i][2] + bb.z,
          c3 = acc[i][3] + bb.w;
    if (d == rd) {
      rv0 = fmaxf(rv0, c0); rv1 = fmaxf(rv1, c1);
      rv2 = fmaxf(rv2, c2); rv3 = fmaxf(rv3, c3);
    } else {
      if (rd >= 0) {
        float* p = &x0[(size_t)rd * 128 + (tx << 2)];
        atomicMaxF(p + 0, rv0); atomicMaxF(p + 1, rv1);
        atomicMaxF(p + 2, rv2); atomicMaxF(p + 3, rv3);
      }
      rd = d; rv0 = c0; rv1 = c1; rv2 = c2; rv3 = c3;
    }
  }
  if (rd >= 0) {
    float* p = &x0[(size_t)rd * 128 + (tx << 2)];
    atomicMaxF(p + 0, rv0); atomicMaxF(p + 1, rv1);
    atomicMaxF(p + 2, rv2); atomicMaxF(p + 3, rv3);
  }
}

__global__ __launch_bounds__(256) void k_finalize(float* p, int n) {
  int i = blockIdx.x * 256 + threadIdx.x;
  if (i < n) {
    float v = p[i];
    if (v == -INFINITY) p[i] = 0.f;
  }
}

// ---------------- GAT attention logits: al[n][4] = {as_h0, as_h1, ad_h0, ad_h1} ----------------
__global__ __launch_bounds__(256) void k_att(const float* __restrict__ Hf,
                                             const float* __restrict__ a_s,
                                             const float* __restrict__ a_d,
                                             float* __restrict__ al, int N) {
  int wave = threadIdx.x >> 6, lane = threadIdx.x & 63;
  int i = blockIdx.x * 4 + wave;
  if (i >= N) return;
  float p0 = 0.f, p1 = 0.f, p2 = 0.f, p3 = 0.f;
  #pragma unroll
  for (int c = lane; c < 128; c += 64) {
    float h0 = Hf[(size_t)i * 256 + c];
    float h1 = Hf[(size_t)i * 256 + 128 + c];
    p0 += h0 * a_s[c];
    p1 += h1 * a_s[128 + c];
    p2 += h0 * a_d[c];
    p3 += h1 * a_d[128 + c];
  }
  #pragma unroll
  for (int o = 32; o; o >>= 1) {
    p0 += __shfl_xor(p0, o); p1 += __shfl_xor(p1, o);
    p2 += __shfl_xor(p2, o); p3 += __shfl_xor(p3, o);
  }
  if (lane == 0) {
    al[i * 4 + 0] = p0; al[i * 4 + 1] = p1;
    al[i * 4 + 2] = p2; al[i * 4 + 3] = p3;
  }
}

// ---------------- GAT segment softmax + aggregation, one wave per node ----------------
__global__ __launch_bounds__(256) void k_gat_agg(const float* __restrict__ Hf,
                                                 const float* __restrict__ al,
                                                 const int* __restrict__ rs,
                                                 const int* __restrict__ csr_src,
                                                 const float* __restrict__ bias,
                                                 const float* __restrict__ res,
                                                 float* __restrict__ out, int N) {
  int wave = threadIdx.x >> 6, lane = threadIdx.x & 63;
  int i = blockIdx.x * 4 + wave;
  if (i >= N) return;
  int beg = rs[i], end = rs[i + 1];
  float ad0 = al[i * 4 + 2], ad1 = al[i * 4 + 3];
  float sl0 = leaky(al[i * 4 + 0] + ad0);
  float sl1 = leaky(al[i * 4 + 1] + ad1);
  // pass 1: max (self loop included in init)
  float m0 = sl0, m1 = sl1;
  for (int e = beg + lane; e < end; e += 64) {
    int s = csr_src[e];
    m0 = fmaxf(m0, leaky(al[s * 4 + 0] + ad0));
    m1 = fmaxf(m1, leaky(al[s * 4 + 1] + ad1));
  }
  #pragma unroll
  for (int o = 32; o; o >>= 1) {
    m0 = fmaxf(m0, __shfl_xor(m0, o));
    m1 = fmaxf(m1, __shfl_xor(m1, o));
  }
  // pass 2: sum of exp
  float s0 = 0.f, s1 = 0.f;
  for (int e = beg + lane; e < end; e += 64) {
    int s = csr_src[e];
    s0 += __expf(leaky(al[s * 4 + 0] + ad0) - m0);
    s1 += __expf(leaky(al[s * 4 + 1] + ad1) - m1);
  }
  #pragma unroll
  for (int o = 32; o; o >>= 1) {
    s0 += __shfl_xor(s0, o);
    s1 += __shfl_xor(s1, o);
  }
  s0 += __expf(sl0 - m0);
  s1 += __expf(sl1 - m1);
  float inv0 = 1.f / (s0 + 1e-16f), inv1 = 1.f / (s1 + 1e-16f);
  // pass 3: weighted feature gather; lane owns 4 contiguous channels
  int c = lane << 2;
  int hsel = lane >> 5;  // head 0 for lanes 0..31, head 1 for 32..63
  float mh = hsel ? m1 : m0;
  float invh = hsel ? inv1 : inv0;
  float adh = hsel ? ad1 : ad0;
  float wself = __expf((hsel ? sl1 : sl0) - mh) * invh;
  float4 hv = *(const float4*)&Hf[(size_t)i * 256 + c];
  float a0 = wself * hv.x, a1 = wself * hv.y, a2 = wself * hv.z, a3 = wself * hv.w;
  for (int e = beg; e < end; ++e) {
    int s = csr_src[e];
    float w = __expf(leaky(al[s * 4 + hsel] + adh) - mh) * invh;
    float4 hv2 = *(const float4*)&Hf[(size_t)s * 256 + c];
    a0 += w * hv2.x; a1 += w * hv2.y; a2 += w * hv2.z; a3 += w * hv2.w;
  }
  float4 bv = *(const float4*)&bias[c];
  float4 o4;
  o4.x = fmaxf(a0 + bv.x, 0.f);
  o4.y = fmaxf(a1 + bv.y, 0.f);
  o4.z = fmaxf(a2 + bv.z, 0.f);
  o4.w = fmaxf(a3 + bv.w, 0.f);
  if (res) {
    float4 r4 = *(const float4*)&res[(size_t)i * 256 + c];
    o4.x += r4.x; o4.y += r4.y; o4.z += r4.z; o4.w += r4.w;
  }
  *(float4*)&out[(size_t)i * 256 + c] = o4;
}

// ---------------- final projection: out[n] = dot(x[n,:256], fin_w) + fin_b ----------------
__global__ __launch_bounds__(256) void k_findot(const float* __restrict__ X,
                                                const float* __restrict__ fw,
                                                const float* __restrict__ fb,
                                                float* __restrict__ out, int N) {
  int wave = threadIdx.x >> 6, lane = threadIdx.x & 63;
  int i = blockIdx.x * 4 + wave;
  if (i >= N) return;
  float4 xv = *(const float4*)&X[(size_t)i * 256 + (lane << 2)];
  float4 wv = *(const float4*)&fw[lane << 2];
  float p = xv.x * wv.x + xv.y * wv.y + xv.z * wv.z + xv.w * wv.w;
  #pragma unroll
  for (int o = 32; o; o >>= 1) p += __shfl_xor(p, o);
  if (lane == 0) out[i] = p + fb[0];
}

// ---------------------------------------------------------------------------
extern "C" void kernel_launch(void* const* d_in, const int* in_sizes, int n_in,
                              void* d_out, int out_size, void* d_ws, size_t ws_size,
                              hipStream_t stream) {
  const float* x      = (const float*)d_in[0];
  const int*   ei     = (const int*)d_in[1];
  const float* ec_w1  = (const float*)d_in[3];
  const float* ec_b1  = (const float*)d_in[4];
  const float* ec_w2  = (const float*)d_in[5];
  const float* ec_b2  = (const float*)d_in[6];
  const float* reg_w  = (const float*)d_in[7];
  const float* reg_b  = (const float*)d_in[8];
  const float* fin_w  = (const float*)d_in[9];
  const float* fin_b  = (const float*)d_in[10];
  const float* g1_w   = (const float*)d_in[11];
  const float* g1_as  = (const float*)d_in[12];
  const float* g1_ad  = (const float*)d_in[13];
  const float* g1_b   = (const float*)d_in[14];
  const float* g2_w   = (const float*)d_in[15];
  const float* g2_as  = (const float*)d_in[16];
  const float* g2_ad  = (const float*)d_in[17];
  const float* g2_b   = (const float*)d_in[18];
  const float* g3_w   = (const float*)d_in[19];
  const float* g3_as  = (const float*)d_in[20];
  const float* g3_ad  = (const float*)d_in[21];
  const float* g3_b   = (const float*)d_in[22];
  const float* g4_w   = (const float*)d_in[23];
  const float* g4_as  = (const float*)d_in[24];
  const float* g4_ad  = (const float*)d_in[25];
  const float* g4_b   = (const float*)d_in[26];

  const int N = in_sizes[0] / 128;
  const int E = in_sizes[1] / 2;

  // workspace layout
  char* base = (char*)d_ws;
  size_t off = 0;
  auto alloc = [&](size_t bytes) -> char* {
    char* p = base + off;
    off += (bytes + 255) & ~(size_t)255;
    return p;
  };
  int*   deg      = (int*)alloc((size_t)N * 4);
  int*   cnt      = (int*)alloc((size_t)N * 4);
  int*   rs       = (int*)alloc((size_t)(N + 1) * 4);
  int*   csr_src  = (int*)alloc((size_t)E * 4);
  int*   csr_dst  = (int*)alloc((size_t)E * 4);
  float* Bcat     = (float*)alloc(128 * 256 * 4);
  float* bias_cat = (float*)alloc(256 * 4);
  float* uv       = (float*)alloc((size_t)N * 256 * 4);  // reused as H buffer
  float* x0       = (float*)alloc((size_t)N * 128 * 4);
  float* X1       = (float*)alloc((size_t)N * 256 * 4);
  float* X2       = (float*)alloc((size_t)N * 256 * 4);
  float* al       = (float*)alloc((size_t)N * 4 * 4);
  (void)ws_size; (void)n_in; (void)out_size;

  const int nodeWaveBlocks = (N + 3) / 4;

  // --- CSR build ---
  k_zero_int<<<(N + 255) / 256, 256, 0, stream>>>(deg, N);
  k_zero_int<<<(N + 255) / 256, 256, 0, stream>>>(cnt, N);
  k_hist<<<(E + 255) / 256, 256, 0, stream>>>(ei, deg, E);
  k_scan<<<1, 1024, 0, stream>>>(deg, rs, N);
  k_scatter<<<(E + 255) / 256, 256, 0, stream>>>(ei, rs, cnt, csr_src, csr_dst, E);

  // --- EdgeConv ---
  k_prep<<<128, 256, 0, stream>>>(ec_w1, ec_b1, Bcat, bias_cat);
  {
    dim3 g((N + GBM - 1) / GBM, 256 / GBN);
    k_gemm<<<g, 256, 0, stream>>>(x, Bcat, bias_cat, uv, N, 128, 256);
  }
  k_fill_f32<<<(N * 128 + 255) / 256, 256, 0, stream>>>(x0, -INFINITY, N * 128);
  k_edgeconv<<<(E + 63) / 64, 256, 0, stream>>>(uv, csr_src, csr_dst, ec_w2, ec_b2, x0, E);
  k_finalize<<<(N * 128 + 255) / 256, 256, 0, stream>>>(x0, N * 128);

  // --- GAT1: X1 = relu(gat(x0)) ---
  {
    dim3 g((N + GBM - 1) / GBM, 256 / GBN);
    k_gemm<<<g, 256, 0, stream>>>(x0, g1_w, nullptr, uv, N, 128, 256);
  }
  k_att<<<nodeWaveBlocks, 256, 0, stream>>>(uv, g1_as, g1_ad, al, N);
  k_gat_agg<<<nodeWaveBlocks, 256, 0, stream>>>(uv, al, rs, csr_src, g1_b, nullptr, X1, N);

  // --- GAT2: X2 = relu(gat(X1)) + X1 ---
  {
    dim3 g((N + GBM - 1) / GBM, 256 / GBN);
    k_gemm<<<g, 256, 0, stream>>>(X1, g2_w, nullptr, uv, N, 256, 256);
  }
  k_att<<<nodeWaveBlocks, 256, 0, stream>>>(uv, g2_as, g2_ad, al, N);
  k_gat_agg<<<nodeWaveBlocks, 256, 0, stream>>>(uv, al, rs, csr_src, g2_b, X1, X2, N);

  // --- reg: X1 = X2 @ reg_w + reg_b ---
  {
    dim3 g((N + GBM - 1) / GBM, 256 / GBN);
    k_gemm<<<g, 256, 0, stream>>>(X2, reg_w, reg_b, X1, N, 256, 256);
  }

  // --- GAT3: X2 = relu(gat(X1)) + X1 ---
  {
    dim3 g((N + GBM - 1) / GBM, 256 / GBN);
    k_gemm<<<g, 256, 0, stream>>>(X1, g3_w, nullptr, uv, N, 256, 256);
  }
  k_att<<<nodeWaveBlocks, 256, 0, stream>>>(uv, g3_as, g3_ad, al, N);
  k_gat_agg<<<nodeWaveBlocks, 256, 0, stream>>>(uv, al, rs, csr_src, g3_b, X1, X2, N);

  // --- GAT4: X1 = relu(gat(X2)) ---
  {
    dim3 g((N + GBM - 1) / GBM, 256 / GBN);
    k_gemm<<<g, 256, 0, stream>>>(X2, g4_w, nullptr, uv, N, 256, 256);
  }
  k_att<<<nodeWaveBlocks, 256, 0, stream>>>(uv, g4_as, g4_ad, al, N);
  k_gat_agg<<<nodeWaveBlocks, 256, 0, stream>>>(uv, al, rs, csr_src, g4_b, nullptr, X1, N);

  // --- final linear ---
  k_findot<<<nodeWaveBlocks, 256, 0, stream>>>(X1, fin_w, fin_b, (float*)d_out, N);
}

// Round 2
// 706.016 us; speedup vs baseline: 1.2633x; 1.2633x over previous
//
#include <hip/hip_runtime.h>
#include <math.h>

// ---------------------------------------------------------------------------
// SymmetricalResidualGAT: EdgeConv(max) + GAT x4 (H=2, C=128) + linears.
// N=20000, E=320000, F=128, HID=128, OC=256.
// Round 2: all GEMM-shaped work on MFMA bf16 with 3-term split (hi/lo) for
// fp32-equivalent accuracy; EdgeConv merges dst-runs in LDS before atomics.
// ---------------------------------------------------------------------------

#define NEG_SLOPE 0.2f

typedef short short8 __attribute__((ext_vector_type(8)));
typedef float float4v __attribute__((ext_vector_type(4)));

__device__ __forceinline__ float leaky(float x) { return x > 0.f ? x : NEG_SLOPE * x; }

__device__ __forceinline__ void atomicMaxF(float* addr, float v) {
  if (v >= 0.f) atomicMax((int*)addr, __float_as_int(v));
  else          atomicMin((unsigned int*)addr, __float_as_uint(v));
}

__device__ __forceinline__ unsigned short bf16_rn(float f) {
  unsigned u = __float_as_uint(f);
  unsigned r = (u + 0x7FFFu + ((u >> 16) & 1u)) >> 16;
  return (unsigned short)r;
}
__device__ __forceinline__ float bf16_to_f(unsigned short h) {
  return __uint_as_float(((unsigned)h) << 16);
}

// ---------------- utility kernels ----------------
__global__ __launch_bounds__(256) void k_zero_int(int* p, int n) {
  int i = blockIdx.x * 256 + threadIdx.x;
  if (i < n) p[i] = 0;
}

__global__ __launch_bounds__(256) void k_fill_f32(float* p, float v, int n) {
  int i = blockIdx.x * 256 + threadIdx.x;
  if (i < n) p[i] = v;
}

__global__ __launch_bounds__(256) void k_hist(const int* __restrict__ ei, int* __restrict__ deg,
                                              int E) {
  int e = blockIdx.x * 256 + threadIdx.x;
  if (e < E) atomicAdd(&deg[ei[E + e]], 1);
}

__global__ __launch_bounds__(1024) void k_scan(const int* __restrict__ deg, int* __restrict__ rs,
                                               int n) {
  __shared__ int buf[1024];
  __shared__ int carry_s;
  int tid = threadIdx.x;
  if (tid == 0) carry_s = 0;
  __syncthreads();
  for (int base = 0; base < n; base += 1024) {
    int i = base + tid;
    int v = (i < n) ? deg[i] : 0;
    buf[tid] = v;
    __syncthreads();
    for (int off = 1; off < 1024; off <<= 1) {
      int t = (tid >= off) ? buf[tid - off] : 0;
      __syncthreads();
      buf[tid] += t;
      __syncthreads();
    }
    int carry = carry_s;
    if (i < n) rs[i] = carry + buf[tid] - v;  // exclusive
    __syncthreads();
    if (tid == 1023) carry_s = carry + buf[1023];
    __syncthreads();
  }
  if (tid == 0) rs[n] = carry_s;
}

__global__ __launch_bounds__(256) void k_scatter(const int* __restrict__ ei,
                                                 const int* __restrict__ rs,
                                                 int* __restrict__ cnt,
                                                 int* __restrict__ csr_src,
                                                 int* __restrict__ csr_dst, int E) {
  int e = blockIdx.x * 256 + threadIdx.x;
  if (e < E) {
    int d = ei[E + e];
    int p = atomicAdd(&cnt[d], 1);
    int slot = rs[d] + p;
    csr_src[slot] = ei[e];
    csr_dst[slot] = d;
  }
}

// Build EdgeConv combined layer-1 weight, TRANSPOSED + split:
// BcatT[n][k]: n<128 -> W1[k][n]-W1[k+128][n] ; n>=128 -> W1[k+128][n-128]
__global__ __launch_bounds__(256) void k_prep2(const float* __restrict__ w1,
                                               const float* __restrict__ b1,
                                               unsigned short* __restrict__ BTh,
                                               unsigned short* __restrict__ BTl,
                                               float* __restrict__ bias_cat) {
  int idx = blockIdx.x * 256 + threadIdx.x;  // 0..32767
  int n = idx >> 7;
  int k = idx & 127;
  float v;
  if (n < 128) v = w1[k * 128 + n] - w1[(k + 128) * 128 + n];
  else         v = w1[(k + 128) * 128 + (n - 128)];
  unsigned short h = bf16_rn(v);
  BTh[idx] = h;
  BTl[idx] = bf16_rn(v - bf16_to_f(h));
  if (idx < 256) bias_cat[idx] = (idx < 128) ? b1[idx] : 0.f;
}

// Transpose + split a weight matrix W[K][N] -> WT_h/WT_l [N][K] (bf16)
__global__ __launch_bounds__(256) void k_split_wT(const float* __restrict__ W,
                                                  unsigned short* __restrict__ WTh,
                                                  unsigned short* __restrict__ WTl,
                                                  int K, int N) {
  int idx = blockIdx.x * 256 + threadIdx.x;
  if (idx >= K * N) return;
  int n = idx / K;
  int k = idx - n * K;
  float v = W[k * N + n];
  unsigned short h = bf16_rn(v);
  WTh[idx] = h;
  WTl[idx] = bf16_rn(v - bf16_to_f(h));
}

// ---------------- MFMA split-bf16 GEMM: C[M][256] = A[M][K] @ W[K][256] (+bias) ----------
// BT_h/BT_l are W transposed+split: [256][K] bf16. A split in-kernel.
// Block: 256 thr, tile BM=64 x BN=128, BK=32. Grid (ceil(M/64), 2).
__global__ __launch_bounds__(256) void k_gemm_mfma(const float* __restrict__ A,
                                                   const unsigned short* __restrict__ BTh,
                                                   const unsigned short* __restrict__ BTl,
                                                   const float* __restrict__ bias,
                                                   float* __restrict__ C, int M, int K) {
  __shared__ __align__(16) unsigned short Ash[64][40];
  __shared__ __align__(16) unsigned short Asl[64][40];
  __shared__ __align__(16) unsigned short Bsh[128][40];
  __shared__ __align__(16) unsigned short Bsl[128][40];
  const int tid = threadIdx.x;
  const int bm = blockIdx.x * 64;
  const int bn = blockIdx.y * 128;
  const int w = tid >> 6, lane = tid & 63, quad = lane >> 4, lr = lane & 15;
  float4v zero4 = {0.f, 0.f, 0.f, 0.f};
  float4v acc[4][2];
  #pragma unroll
  for (int mt = 0; mt < 4; ++mt)
    #pragma unroll
    for (int nt = 0; nt < 2; ++nt) acc[mt][nt] = zero4;

  const int arow = tid >> 2;
  const int akq = (tid & 3) * 8;
  const int agr = bm + arow;

  for (int k0 = 0; k0 < K; k0 += 32) {
    // ---- stage A (fp32 -> split bf16) ----
    float av[8];
    if (agr < M) {
      float4 a0 = *(const float4*)&A[(size_t)agr * K + k0 + akq];
      float4 a1 = *(const float4*)&A[(size_t)agr * K + k0 + akq + 4];
      av[0] = a0.x; av[1] = a0.y; av[2] = a0.z; av[3] = a0.w;
      av[4] = a1.x; av[5] = a1.y; av[6] = a1.z; av[7] = a1.w;
    } else {
      #pragma unroll
      for (int i = 0; i < 8; ++i) av[i] = 0.f;
    }
    short8 h8, l8;
    #pragma unroll
    for (int i = 0; i < 8; ++i) {
      unsigned short h = bf16_rn(av[i]);
      h8[i] = (short)h;
      l8[i] = (short)bf16_rn(av[i] - bf16_to_f(h));
    }
    *(short8*)&Ash[arow][akq] = h8;
    *(short8*)&Asl[arow][akq] = l8;
    // ---- stage B (pre-split bf16) ----
    #pragma unroll
    for (int c = tid; c < 512; c += 256) {
      int n = c >> 2, kq2 = (c & 3) * 8;
      *(short8*)&Bsh[n][kq2] = *(const short8*)&BTh[(size_t)(bn + n) * K + k0 + kq2];
      *(short8*)&Bsl[n][kq2] = *(const short8*)&BTl[(size_t)(bn + n) * K + k0 + kq2];
    }
    __syncthreads();
    short8 ah[4], alo[4], bh[2], blo[2];
    #pragma unroll
    for (int mt = 0; mt < 4; ++mt) {
      ah[mt]  = *(short8*)&Ash[mt * 16 + lr][quad * 8];
      alo[mt] = *(short8*)&Asl[mt * 16 + lr][quad * 8];
    }
    #pragma unroll
    for (int nt = 0; nt < 2; ++nt) {
      bh[nt]  = *(short8*)&Bsh[w * 32 + nt * 16 + lr][quad * 8];
      blo[nt] = *(short8*)&Bsl[w * 32 + nt * 16 + lr][quad * 8];
    }
    #pragma unroll
    for (int mt = 0; mt < 4; ++mt)
      #pragma unroll
      for (int nt = 0; nt < 2; ++nt) {
        acc[mt][nt] = __builtin_amdgcn_mfma_f32_16x16x32_bf16(ah[mt], bh[nt], acc[mt][nt], 0, 0, 0);
        acc[mt][nt] = __builtin_amdgcn_mfma_f32_16x16x32_bf16(alo[mt], bh[nt], acc[mt][nt], 0, 0, 0);
        acc[mt][nt] = __builtin_amdgcn_mfma_f32_16x16x32_bf16(ah[mt], blo[nt], acc[mt][nt], 0, 0, 0);
      }
    __syncthreads();
  }
  // ---- epilogue: C layout col=lane&15, row=quad*4+reg ----
  #pragma unroll
  for (int nt = 0; nt < 2; ++nt) {
    int n = bn + w * 32 + nt * 16 + lr;
    float bv = bias ? bias[n] : 0.f;
    #pragma unroll
    for (int mt = 0; mt < 4; ++mt) {
      #pragma unroll
      for (int r = 0; r < 4; ++r) {
        int m = bm + mt * 16 + quad * 4 + r;
        if (m < M) C[(size_t)m * 256 + n] = acc[mt][nt][r] + bv;
      }
    }
  }
}

// ---------------- EdgeConv: P=relu(u[dst]+v[src]); H2=P@W2+b2; segment-max ----------------
// 64 edges/block; MFMA split-bf16; LDS run-merge before atomics.
__global__ __launch_bounds__(256) void k_edgeconv2(const float* __restrict__ uv,
                                                   const int* __restrict__ csr_src,
                                                   const int* __restrict__ csr_dst,
                                                   const unsigned short* __restrict__ w2Th,
                                                   const unsigned short* __restrict__ w2Tl,
                                                   const float* __restrict__ b2,
                                                   float* __restrict__ x0, int E) {
  __shared__ __align__(16) char smem[55296];
  unsigned short (*Ph)[136] = (unsigned short(*)[136])smem;            // 17408 B
  unsigned short (*Pl)[136] = (unsigned short(*)[136])(smem + 17408);  // 17408 B
  float (*H2)[132] = (float(*)[132])smem;                              // 33792 B (alias)
  unsigned short (*W2h)[40] = (unsigned short(*)[40])(smem + 34816);   // 10240 B
  unsigned short (*W2l)[40] = (unsigned short(*)[40])(smem + 45056);   // 10240 B
  __shared__ int sSrc[64], sDst[64];

  const int tid = threadIdx.x;
  const int e0 = blockIdx.x * 64;
  const int w = tid >> 6, lane = tid & 63, quad = lane >> 4, lr = lane & 15;
  if (tid < 64) {
    int e = e0 + tid;
    sSrc[tid] = (e < E) ? csr_src[e] : -1;
    sDst[tid] = (e < E) ? csr_dst[e] : -1;
  }
  __syncthreads();
  // ---- build P (64 x 128) split bf16 ----
  #pragma unroll
  for (int c = tid; c < 1024; c += 256) {
    int r = c >> 4;
    int kq = (c & 15) * 8;
    float pv[8];
    int sn = sSrc[r], dn = sDst[r];
    if (sn >= 0) {
      float4 u0 = *(const float4*)&uv[(size_t)dn * 256 + kq];
      float4 u1 = *(const float4*)&uv[(size_t)dn * 256 + kq + 4];
      float4 v0 = *(const float4*)&uv[(size_t)sn * 256 + 128 + kq];
      float4 v1 = *(const float4*)&uv[(size_t)sn * 256 + 128 + kq + 4];
      pv[0] = fmaxf(u0.x + v0.x, 0.f); pv[1] = fmaxf(u0.y + v0.y, 0.f);
      pv[2] = fmaxf(u0.z + v0.z, 0.f); pv[3] = fmaxf(u0.w + v0.w, 0.f);
      pv[4] = fmaxf(u1.x + v1.x, 0.f); pv[5] = fmaxf(u1.y + v1.y, 0.f);
      pv[6] = fmaxf(u1.z + v1.z, 0.f); pv[7] = fmaxf(u1.w + v1.w, 0.f);
    } else {
      #pragma unroll
      for (int i = 0; i < 8; ++i) pv[i] = 0.f;
    }
    short8 h8, l8;
    #pragma unroll
    for (int i = 0; i < 8; ++i) {
      unsigned short h = bf16_rn(pv[i]);
      h8[i] = (short)h;
      l8[i] = (short)bf16_rn(pv[i] - bf16_to_f(h));
    }
    *(short8*)&Ph[r][kq] = h8;
    *(short8*)&Pl[r][kq] = l8;
  }
  float4v zero4 = {0.f, 0.f, 0.f, 0.f};
  float4v acc[4][2];
  #pragma unroll
  for (int mt = 0; mt < 4; ++mt)
    #pragma unroll
    for (int nt = 0; nt < 2; ++nt) acc[mt][nt] = zero4;

  for (int k0 = 0; k0 < 128; k0 += 32) {
    __syncthreads();
    // stage W2T slice [128 n][32 k] hi/lo
    #pragma unroll
    for (int c = tid; c < 512; c += 256) {
      int n = c >> 2, kq2 = (c & 3) * 8;
      *(short8*)&W2h[n][kq2] = *(const short8*)&w2Th[(size_t)n * 128 + k0 + kq2];
      *(short8*)&W2l[n][kq2] = *(const short8*)&w2Tl[(size_t)n * 128 + k0 + kq2];
    }
    __syncthreads();
    short8 ah[4], alo[4], bh[2], blo[2];
    #pragma unroll
    for (int mt = 0; mt < 4; ++mt) {
      ah[mt]  = *(short8*)&Ph[mt * 16 + lr][k0 + quad * 8];
      alo[mt] = *(short8*)&Pl[mt * 16 + lr][k0 + quad * 8];
    }
    #pragma unroll
    for (int nt = 0; nt < 2; ++nt) {
      bh[nt]  = *(short8*)&W2h[w * 32 + nt * 16 + lr][quad * 8];
      blo[nt] = *(short8*)&W2l[w * 32 + nt * 16 + lr][quad * 8];
    }
    #pragma unroll
    for (int mt = 0; mt < 4; ++mt)
      #pragma unroll
      for (int nt = 0; nt < 2; ++nt) {
        acc[mt][nt] = __builtin_amdgcn_mfma_f32_16x16x32_bf16(ah[mt], bh[nt], acc[mt][nt], 0, 0, 0);
        acc[mt][nt] = __builtin_amdgcn_mfma_f32_16x16x32_bf16(alo[mt], bh[nt], acc[mt][nt], 0, 0, 0);
        acc[mt][nt] = __builtin_amdgcn_mfma_f32_16x16x32_bf16(ah[mt], blo[nt], acc[mt][nt], 0, 0, 0);
      }
  }
  __syncthreads();  // P/W2 dead; reuse region as H2
  #pragma unroll
  for (int nt = 0; nt < 2; ++nt) {
    int n = w * 32 + nt * 16 + lr;
    float bv = b2[n];
    #pragma unroll
    for (int mt = 0; mt < 4; ++mt) {
      #pragma unroll
      for (int r = 0; r < 4; ++r) {
        int row = mt * 16 + quad * 4 + r;
        H2[row][n] = acc[mt][nt][r] + bv;
      }
    }
  }
  __syncthreads();
  // run-merge over sorted dst, one thread per channel
  if (tid < 128) {
    int col = tid;
    int prev = sDst[0];
    float rmax = H2[0][col];
    for (int r = 1; r < 64; ++r) {
      int d = sDst[r];
      float v = H2[r][col];
      if (d == prev) {
        rmax = fmaxf(rmax, v);
      } else {
        if (prev >= 0) atomicMaxF(&x0[(size_t)prev * 128 + col], rmax);
        prev = d;
        rmax = v;
      }
    }
    if (prev >= 0) atomicMaxF(&x0[(size_t)prev * 128 + col], rmax);
  }
}

__global__ __launch_bounds__(256) void k_finalize(float* p, int n) {
  int i = blockIdx.x * 256 + threadIdx.x;
  if (i < n) {
    float v = p[i];
    if (v == -INFINITY) p[i] = 0.f;
  }
}

// ---------------- GAT attention logits: al[n][4] = {as_h0, as_h1, ad_h0, ad_h1} ----------
__global__ __launch_bounds__(256) void k_att(const float* __restrict__ Hf,
                                             const float* __restrict__ a_s,
                                             const float* __restrict__ a_d,
                                             float* __restrict__ al, int N) {
  int wave = threadIdx.x >> 6, lane = threadIdx.x & 63;
  int i = blockIdx.x * 4 + wave;
  if (i >= N) return;
  float p0 = 0.f, p1 = 0.f, p2 = 0.f, p3 = 0.f;
  #pragma unroll
  for (int c = lane; c < 128; c += 64) {
    float h0 = Hf[(size_t)i * 256 + c];
    float h1 = Hf[(size_t)i * 256 + 128 + c];
    p0 += h0 * a_s[c];
    p1 += h1 * a_s[128 + c];
    p2 += h0 * a_d[c];
    p3 += h1 * a_d[128 + c];
  }
  #pragma unroll
  for (int o = 32; o; o >>= 1) {
    p0 += __shfl_xor(p0, o); p1 += __shfl_xor(p1, o);
    p2 += __shfl_xor(p2, o); p3 += __shfl_xor(p3, o);
  }
  if (lane == 0) {
    al[i * 4 + 0] = p0; al[i * 4 + 1] = p1;
    al[i * 4 + 2] = p2; al[i * 4 + 3] = p3;
  }
}

// ---------------- GAT segment softmax + aggregation, one wave per node ----------------
__global__ __launch_bounds__(256) void k_gat_agg(const float* __restrict__ Hf,
                                                 const float* __restrict__ al,
                                                 const int* __restrict__ rs,
                                                 const int* __restrict__ csr_src,
                                                 const float* __restrict__ bias,
                                                 const float* __restrict__ res,
                                                 float* __restrict__ out, int N) {
  int wave = threadIdx.x >> 6, lane = threadIdx.x & 63;
  int i = blockIdx.x * 4 + wave;
  if (i >= N) return;
  int beg = rs[i], end = rs[i + 1];
  float ad0 = al[i * 4 + 2], ad1 = al[i * 4 + 3];
  float sl0 = leaky(al[i * 4 + 0] + ad0);
  float sl1 = leaky(al[i * 4 + 1] + ad1);
  float m0 = sl0, m1 = sl1;
  for (int e = beg + lane; e < end; e += 64) {
    int s = csr_src[e];
    m0 = fmaxf(m0, leaky(al[s * 4 + 0] + ad0));
    m1 = fmaxf(m1, leaky(al[s * 4 + 1] + ad1));
  }
  #pragma unroll
  for (int o = 32; o; o >>= 1) {
    m0 = fmaxf(m0, __shfl_xor(m0, o));
    m1 = fmaxf(m1, __shfl_xor(m1, o));
  }
  float s0 = 0.f, s1 = 0.f;
  for (int e = beg + lane; e < end; e += 64) {
    int s = csr_src[e];
    s0 += __expf(leaky(al[s * 4 + 0] + ad0) - m0);
    s1 += __expf(leaky(al[s * 4 + 1] + ad1) - m1);
  }
  #pragma unroll
  for (int o = 32; o; o >>= 1) {
    s0 += __shfl_xor(s0, o);
    s1 += __shfl_xor(s1, o);
  }
  s0 += __expf(sl0 - m0);
  s1 += __expf(sl1 - m1);
  float inv0 = 1.f / (s0 + 1e-16f), inv1 = 1.f / (s1 + 1e-16f);
  int c = lane << 2;
  int hsel = lane >> 5;
  float mh = hsel ? m1 : m0;
  float invh = hsel ? inv1 : inv0;
  float adh = hsel ? ad1 : ad0;
  float wself = __expf((hsel ? sl1 : sl0) - mh) * invh;
  float4 hv = *(const float4*)&Hf[(size_t)i * 256 + c];
  float a0 = wself * hv.x, a1 = wself * hv.y, a2 = wself * hv.z, a3 = wself * hv.w;
  for (int e = beg; e < end; ++e) {
    int s = csr_src[e];
    float wgt = __expf(leaky(al[s * 4 + hsel] + adh) - mh) * invh;
    float4 hv2 = *(const float4*)&Hf[(size_t)s * 256 + c];
    a0 += wgt * hv2.x; a1 += wgt * hv2.y; a2 += wgt * hv2.z; a3 += wgt * hv2.w;
  }
  float4 bv = *(const float4*)&bias[c];
  float4 o4;
  o4.x = fmaxf(a0 + bv.x, 0.f);
  o4.y = fmaxf(a1 + bv.y, 0.f);
  o4.z = fmaxf(a2 + bv.z, 0.f);
  o4.w = fmaxf(a3 + bv.w, 0.f);
  if (res) {
    float4 r4 = *(const float4*)&res[(size_t)i * 256 + c];
    o4.x += r4.x; o4.y += r4.y; o4.z += r4.z; o4.w += r4.w;
  }
  *(float4*)&out[(size_t)i * 256 + c] = o4;
}

// ---------------- final projection ----------------
__global__ __launch_bounds__(256) void k_findot(const float* __restrict__ X,
                                                const float* __restrict__ fw,
                                                const float* __restrict__ fb,
                                                float* __restrict__ out, int N) {
  int wave = threadIdx.x >> 6, lane = threadIdx.x & 63;
  int i = blockIdx.x * 4 + wave;
  if (i >= N) return;
  float4 xv = *(const float4*)&X[(size_t)i * 256 + (lane << 2)];
  float4 wv = *(const float4*)&fw[lane << 2];
  float p = xv.x * wv.x + xv.y * wv.y + xv.z * wv.z + xv.w * wv.w;
  #pragma unroll
  for (int o = 32; o; o >>= 1) p += __shfl_xor(p, o);
  if (lane == 0) out[i] = p + fb[0];
}

// ---------------------------------------------------------------------------
extern "C" void kernel_launch(void* const* d_in, const int* in_sizes, int n_in,
                              void* d_out, int out_size, void* d_ws, size_t ws_size,
                              hipStream_t stream) {
  const float* x      = (const float*)d_in[0];
  const int*   ei     = (const int*)d_in[1];
  const float* ec_w1  = (const float*)d_in[3];
  const float* ec_b1  = (const float*)d_in[4];
  const float* ec_w2  = (const float*)d_in[5];
  const float* ec_b2  = (const float*)d_in[6];
  const float* reg_w  = (const float*)d_in[7];
  const float* reg_b  = (const float*)d_in[8];
  const float* fin_w  = (const float*)d_in[9];
  const float* fin_b  = (const float*)d_in[10];
  const float* g1_w   = (const float*)d_in[11];
  const float* g1_as  = (const float*)d_in[12];
  const float* g1_ad  = (const float*)d_in[13];
  const float* g1_b   = (const float*)d_in[14];
  const float* g2_w   = (const float*)d_in[15];
  const float* g2_as  = (const float*)d_in[16];
  const float* g2_ad  = (const float*)d_in[17];
  const float* g2_b   = (const float*)d_in[18];
  const float* g3_w   = (const float*)d_in[19];
  const float* g3_as  = (const float*)d_in[20];
  const float* g3_ad  = (const float*)d_in[21];
  const float* g3_b   = (const float*)d_in[22];
  const float* g4_w   = (const float*)d_in[23];
  const float* g4_as  = (const float*)d_in[24];
  const float* g4_ad  = (const float*)d_in[25];
  const float* g4_b   = (const float*)d_in[26];

  const int N = in_sizes[0] / 128;
  const int E = in_sizes[1] / 2;

  char* base = (char*)d_ws;
  size_t off = 0;
  auto alloc = [&](size_t bytes) -> char* {
    char* p = base + off;
    off += (bytes + 255) & ~(size_t)255;
    return p;
  };
  int*   deg      = (int*)alloc((size_t)N * 4);
  int*   cnt      = (int*)alloc((size_t)N * 4);
  int*   rs       = (int*)alloc((size_t)(N + 1) * 4);
  int*   csr_src  = (int*)alloc((size_t)E * 4);
  int*   csr_dst  = (int*)alloc((size_t)E * 4);
  float* bias_cat = (float*)alloc(256 * 4);
  unsigned short* bcatTh = (unsigned short*)alloc(256 * 128 * 2);
  unsigned short* bcatTl = (unsigned short*)alloc(256 * 128 * 2);
  unsigned short* w2Th   = (unsigned short*)alloc(128 * 128 * 2);
  unsigned short* w2Tl   = (unsigned short*)alloc(128 * 128 * 2);
  unsigned short* g1Th   = (unsigned short*)alloc(256 * 128 * 2);
  unsigned short* g1Tl   = (unsigned short*)alloc(256 * 128 * 2);
  unsigned short* g2Th   = (unsigned short*)alloc(256 * 256 * 2);
  unsigned short* g2Tl   = (unsigned short*)alloc(256 * 256 * 2);
  unsigned short* g3Th   = (unsigned short*)alloc(256 * 256 * 2);
  unsigned short* g3Tl   = (unsigned short*)alloc(256 * 256 * 2);
  unsigned short* g4Th   = (unsigned short*)alloc(256 * 256 * 2);
  unsigned short* g4Tl   = (unsigned short*)alloc(256 * 256 * 2);
  unsigned short* regTh  = (unsigned short*)alloc(256 * 256 * 2);
  unsigned short* regTl  = (unsigned short*)alloc(256 * 256 * 2);
  float* uv = (float*)alloc((size_t)N * 256 * 4);
  float* x0 = (float*)alloc((size_t)N * 128 * 4);
  float* X1 = (float*)alloc((size_t)N * 256 * 4);
  float* X2 = (float*)alloc((size_t)N * 256 * 4);
  float* al = (float*)alloc((size_t)N * 4 * 4);
  (void)ws_size; (void)n_in; (void)out_size;

  const int nodeWaveBlocks = (N + 3) / 4;
  const dim3 gemmGrid((N + 63) / 64, 2);

  // --- CSR build ---
  k_zero_int<<<(N + 255) / 256, 256, 0, stream>>>(deg, N);
  k_zero_int<<<(N + 255) / 256, 256, 0, stream>>>(cnt, N);
  k_hist<<<(E + 255) / 256, 256, 0, stream>>>(ei, deg, E);
  k_scan<<<1, 1024, 0, stream>>>(deg, rs, N);
  k_scatter<<<(E + 255) / 256, 256, 0, stream>>>(ei, rs, cnt, csr_src, csr_dst, E);

  // --- weight prep (transpose + hi/lo split) ---
  k_prep2<<<128, 256, 0, stream>>>(ec_w1, ec_b1, bcatTh, bcatTl, bias_cat);
  k_split_wT<<<64, 256, 0, stream>>>(ec_w2, w2Th, w2Tl, 128, 128);
  k_split_wT<<<128, 256, 0, stream>>>(g1_w, g1Th, g1Tl, 128, 256);
  k_split_wT<<<256, 256, 0, stream>>>(g2_w, g2Th, g2Tl, 256, 256);
  k_split_wT<<<256, 256, 0, stream>>>(g3_w, g3Th, g3Tl, 256, 256);
  k_split_wT<<<256, 256, 0, stream>>>(g4_w, g4Th, g4Tl, 256, 256);
  k_split_wT<<<256, 256, 0, stream>>>(reg_w, regTh, regTl, 256, 256);

  // --- EdgeConv ---
  k_gemm_mfma<<<gemmGrid, 256, 0, stream>>>(x, bcatTh, bcatTl, bias_cat, uv, N, 128);
  k_fill_f32<<<(N * 128 + 255) / 256, 256, 0, stream>>>(x0, -INFINITY, N * 128);
  k_edgeconv2<<<(E + 63) / 64, 256, 0, stream>>>(uv, csr_src, csr_dst, w2Th, w2Tl, ec_b2, x0, E);
  k_finalize<<<(N * 128 + 255) / 256, 256, 0, stream>>>(x0, N * 128);

  // --- GAT1: X1 = relu(gat(x0)) ---
  k_gemm_mfma<<<gemmGrid, 256, 0, stream>>>(x0, g1Th, g1Tl, nullptr, uv, N, 128);
  k_att<<<nodeWaveBlocks, 256, 0, stream>>>(uv, g1_as, g1_ad, al, N);
  k_gat_agg<<<nodeWaveBlocks, 256, 0, stream>>>(uv, al, rs, csr_src, g1_b, nullptr, X1, N);

  // --- GAT2: X2 = relu(gat(X1)) + X1 ---
  k_gemm_mfma<<<gemmGrid, 256, 0, stream>>>(X1, g2Th, g2Tl, nullptr, uv, N, 256);
  k_att<<<nodeWaveBlocks, 256, 0, stream>>>(uv, g2_as, g2_ad, al, N);
  k_gat_agg<<<nodeWaveBlocks, 256, 0, stream>>>(uv, al, rs, csr_src, g2_b, X1, X2, N);

  // --- reg: X1 = X2 @ reg_w + reg_b ---
  k_gemm_mfma<<<gemmGrid, 256, 0, stream>>>(X2, regTh, regTl, reg_b, X1, N, 256);

  // --- GAT3: X2 = relu(gat(X1)) + X1 ---
  k_gemm_mfma<<<gemmGrid, 256, 0, stream>>>(X1, g3Th, g3Tl, nullptr, uv, N, 256);
  k_att<<<nodeWaveBlocks, 256, 0, stream>>>(uv, g3_as, g3_ad, al, N);
  k_gat_agg<<<nodeWaveBlocks, 256, 0, stream>>>(uv, al, rs, csr_src, g3_b, X1, X2, N);

  // --- GAT4: X1 = relu(gat(X2)) ---
  k_gemm_mfma<<<gemmGrid, 256, 0, stream>>>(X2, g4Th, g4Tl, nullptr, uv, N, 256);
  k_att<<<nodeWaveBlocks, 256, 0, stream>>>(uv, g4_as, g4_ad, al, N);
  k_gat_agg<<<nodeWaveBlocks, 256, 0, stream>>>(uv, al, rs, csr_src, g4_b, nullptr, X1, N);

  // --- final linear ---
  k_findot<<<nodeWaveBlocks, 256, 0, stream>>>(X1, fin_w, fin_b, (float*)d_out, N);
}

// Round 3
// 588.868 us; speedup vs baseline: 1.5146x; 1.1989x over previous
//
#include <hip/hip_runtime.h>
#include <math.h>

// ---------------------------------------------------------------------------
// SymmetricalResidualGAT: EdgeConv(max) + GAT x4 (H=2, C=128) + linears.
// N=20000, E=320000. Round 3: occupancy + latency fixes.
//  - edgeconv: W2 B-frags direct from global (LDS 55.8->35.3KB, 1 sync in loop)
//  - gat_agg: lane-parallel softmax, shuffle-broadcast weights, unrolled gather
//  - attention logits fused into GEMM epilogue (k_att removed)
//  - single weight-prep kernel, shuffle-based scan
// ---------------------------------------------------------------------------

#define NEG_SLOPE 0.2f

typedef short short8 __attribute__((ext_vector_type(8)));
typedef float float4v __attribute__((ext_vector_type(4)));

__device__ __forceinline__ float leaky(float x) { return x > 0.f ? x : NEG_SLOPE * x; }

__device__ __forceinline__ void atomicMaxF(float* addr, float v) {
  if (v >= 0.f) atomicMax((int*)addr, __float_as_int(v));
  else          atomicMin((unsigned int*)addr, __float_as_uint(v));
}

__device__ __forceinline__ unsigned short bf16_rn(float f) {
  unsigned u = __float_as_uint(f);
  unsigned r = (u + 0x7FFFu + ((u >> 16) & 1u)) >> 16;
  return (unsigned short)r;
}
__device__ __forceinline__ float bf16_to_f(unsigned short h) {
  return __uint_as_float(((unsigned)h) << 16);
}

// ---------------- small kernels ----------------
__global__ __launch_bounds__(256) void k_fill_f32(float* p, float v, int n) {
  int i = blockIdx.x * 256 + threadIdx.x;
  if (i < n) p[i] = v;
}

__global__ __launch_bounds__(256) void k_hist(const int* __restrict__ ei, int* __restrict__ deg,
                                              int E) {
  int e = blockIdx.x * 256 + threadIdx.x;
  if (e < E) atomicAdd(&deg[ei[E + e]], 1);
}

__global__ __launch_bounds__(1024) void k_scan(const int* __restrict__ deg, int* __restrict__ rs,
                                               int n) {
  __shared__ int wsum[16];
  __shared__ int carry;
  int tid = threadIdx.x, lane = tid & 63, wv = tid >> 6;
  if (tid == 0) carry = 0;
  __syncthreads();
  for (int base = 0; base < n; base += 1024) {
    int i = base + tid;
    int v = (i < n) ? deg[i] : 0;
    int s = v;
    #pragma unroll
    for (int o = 1; o < 64; o <<= 1) {
      int t = __shfl(s, lane - o);
      if (lane >= o) s += t;
    }
    if (lane == 63) wsum[wv] = s;
    __syncthreads();
    if (wv == 0) {
      int x = (lane < 16) ? wsum[lane] : 0;
      #pragma unroll
      for (int o = 1; o < 16; o <<= 1) {
        int t = __shfl(x, lane - o);
        if (lane >= o) x += t;
      }
      if (lane < 16) wsum[lane] = x;
    }
    __syncthreads();
    int woff = carry + (wv ? wsum[wv - 1] : 0);
    if (i < n) rs[i] = woff + s - v;
    __syncthreads();
    if (tid == 0) carry += wsum[15];
    __syncthreads();
  }
  if (tid == 0) rs[n] = carry;
}

__global__ __launch_bounds__(256) void k_scatter(const int* __restrict__ ei,
                                                 const int* __restrict__ rs,
                                                 int* __restrict__ cnt,
                                                 int* __restrict__ csr_src,
                                                 int* __restrict__ csr_dst, int E) {
  int e = blockIdx.x * 256 + threadIdx.x;
  if (e < E) {
    int d = ei[E + e];
    int p = atomicAdd(&cnt[d], 1);
    int slot = rs[d] + p;
    csr_src[slot] = ei[e];
    csr_dst[slot] = d;
  }
}

// ---------------- one-shot weight prep: transpose + hi/lo bf16 split ----------------
struct SplitJob {
  const float* W;
  const float* aux;          // b1 for type 1
  unsigned short* Th;
  unsigned short* Tl;
  float* bias_out;           // type 1 only
  int K, N, kshift, type;    // type 0: WT split; type 1: edgeconv combined W1
};
struct SplitJobs { SplitJob j[7]; };

__global__ __launch_bounds__(256) void k_prep_all(SplitJobs jobs) {
  SplitJob jb = jobs.j[blockIdx.y];
  int idx = blockIdx.x * 256 + threadIdx.x;
  if (idx >= jb.K * jb.N) return;
  float v;
  if (jb.type == 0) {
    int n = idx >> jb.kshift;
    int k = idx & (jb.K - 1);
    v = jb.W[k * jb.N + n];
  } else {
    int n = idx >> 7;
    int k = idx & 127;
    if (n < 128) v = jb.W[k * 128 + n] - jb.W[(k + 128) * 128 + n];
    else         v = jb.W[(k + 128) * 128 + (n - 128)];
    if (idx < 256) jb.bias_out[idx] = (idx < 128) ? jb.aux[idx] : 0.f;
  }
  unsigned short h = bf16_rn(v);
  jb.Th[idx] = h;
  jb.Tl[idx] = bf16_rn(v - bf16_to_f(h));
}

// ---------------- MFMA split-bf16 GEMM + fused attention logits ----------------
// C[M][256] = A[M][K] @ W[K][256] (+bias). BT hi/lo: [256][K] bf16.
// Tile 64x128, 256 thr. Grid (ceil(M/64), 2); block y == head y owns all its cols,
// so al[m][{y,2+y}] is computed exactly with an intra-block reduction.
__global__ __launch_bounds__(256) void k_gemm_mfma(const float* __restrict__ A,
                                                   const unsigned short* __restrict__ BTh,
                                                   const unsigned short* __restrict__ BTl,
                                                   const float* __restrict__ bias,
                                                   float* __restrict__ C, int M, int K,
                                                   const float* __restrict__ a_s,
                                                   const float* __restrict__ a_d,
                                                   float* __restrict__ al_out) {
  __shared__ __align__(16) unsigned short Ash[64][40];
  __shared__ __align__(16) unsigned short Asl[64][40];
  __shared__ __align__(16) unsigned short Bsh[128][40];
  __shared__ __align__(16) unsigned short Bsl[128][40];
  __shared__ float alS[64][2];
  const int tid = threadIdx.x;
  const int bm = blockIdx.x * 64;
  const int bn = blockIdx.y * 128;
  const int w = tid >> 6, lane = tid & 63, quad = lane >> 4, lr = lane & 15;
  float4v zero4 = {0.f, 0.f, 0.f, 0.f};
  float4v acc[4][2];
  #pragma unroll
  for (int mt = 0; mt < 4; ++mt)
    #pragma unroll
    for (int nt = 0; nt < 2; ++nt) acc[mt][nt] = zero4;

  const int arow = tid >> 2;
  const int akq = (tid & 3) * 8;
  const int agr = bm + arow;

  #pragma unroll 4
  for (int k0 = 0; k0 < K; k0 += 32) {
    float av[8];
    if (agr < M) {
      float4 a0 = *(const float4*)&A[(size_t)agr * K + k0 + akq];
      float4 a1 = *(const float4*)&A[(size_t)agr * K + k0 + akq + 4];
      av[0] = a0.x; av[1] = a0.y; av[2] = a0.z; av[3] = a0.w;
      av[4] = a1.x; av[5] = a1.y; av[6] = a1.z; av[7] = a1.w;
    } else {
      #pragma unroll
      for (int i = 0; i < 8; ++i) av[i] = 0.f;
    }
    short8 h8, l8;
    #pragma unroll
    for (int i = 0; i < 8; ++i) {
      unsigned short h = bf16_rn(av[i]);
      h8[i] = (short)h;
      l8[i] = (short)bf16_rn(av[i] - bf16_to_f(h));
    }
    *(short8*)&Ash[arow][akq] = h8;
    *(short8*)&Asl[arow][akq] = l8;
    #pragma unroll
    for (int c = tid; c < 512; c += 256) {
      int n = c >> 2, kq2 = (c & 3) * 8;
      *(short8*)&Bsh[n][kq2] = *(const short8*)&BTh[(size_t)(bn + n) * K + k0 + kq2];
      *(short8*)&Bsl[n][kq2] = *(const short8*)&BTl[(size_t)(bn + n) * K + k0 + kq2];
    }
    __syncthreads();
    short8 ah[4], alo[4], bh[2], blo[2];
    #pragma unroll
    for (int mt = 0; mt < 4; ++mt) {
      ah[mt]  = *(short8*)&Ash[mt * 16 + lr][quad * 8];
      alo[mt] = *(short8*)&Asl[mt * 16 + lr][quad * 8];
    }
    #pragma unroll
    for (int nt = 0; nt < 2; ++nt) {
      bh[nt]  = *(short8*)&Bsh[w * 32 + nt * 16 + lr][quad * 8];
      blo[nt] = *(short8*)&Bsl[w * 32 + nt * 16 + lr][quad * 8];
    }
    #pragma unroll
    for (int mt = 0; mt < 4; ++mt)
      #pragma unroll
      for (int nt = 0; nt < 2; ++nt) {
        acc[mt][nt] = __builtin_amdgcn_mfma_f32_16x16x32_bf16(ah[mt], bh[nt], acc[mt][nt], 0, 0, 0);
        acc[mt][nt] = __builtin_amdgcn_mfma_f32_16x16x32_bf16(alo[mt], bh[nt], acc[mt][nt], 0, 0, 0);
        acc[mt][nt] = __builtin_amdgcn_mfma_f32_16x16x32_bf16(ah[mt], blo[nt], acc[mt][nt], 0, 0, 0);
      }
    __syncthreads();
  }
  // ---- C store (layout col=lane&15, row=quad*4+reg) ----
  #pragma unroll
  for (int nt = 0; nt < 2; ++nt) {
    int n = bn + w * 32 + nt * 16 + lr;
    float bv = bias ? bias[n] : 0.f;
    #pragma unroll
    for (int mt = 0; mt < 4; ++mt) {
      #pragma unroll
      for (int r = 0; r < 4; ++r) {
        int m = bm + mt * 16 + quad * 4 + r;
        if (m < M) C[(size_t)m * 256 + n] = acc[mt][nt][r] + bv;
      }
    }
  }
  // ---- fused attention logits ----
  if (a_s) {
    if (tid < 128) ((float*)alS)[tid] = 0.f;
    __syncthreads();
    float asv[2], adv[2];
    #pragma unroll
    for (int nt = 0; nt < 2; ++nt) {
      int n = bn + w * 32 + nt * 16 + lr;
      asv[nt] = a_s[n];
      adv[nt] = a_d[n];
    }
    #pragma unroll
    for (int mt = 0; mt < 4; ++mt) {
      #pragma unroll
      for (int r = 0; r < 4; ++r) {
        float ps = acc[mt][0][r] * asv[0] + acc[mt][1][r] * asv[1];
        float pd = acc[mt][0][r] * adv[0] + acc[mt][1][r] * adv[1];
        #pragma unroll
        for (int o = 8; o; o >>= 1) {
          ps += __shfl_xor(ps, o);
          pd += __shfl_xor(pd, o);
        }
        if (lr == 0) {
          int row = mt * 16 + quad * 4 + r;
          atomicAdd(&alS[row][0], ps);
          atomicAdd(&alS[row][1], pd);
        }
      }
    }
    __syncthreads();
    int head = bn >> 7;
    if (tid < 64) {
      int m = bm + tid;
      if (m < M) {
        al_out[m * 4 + head]     = alS[tid][0];
        al_out[m * 4 + 2 + head] = alS[tid][1];
      }
    }
  }
}

// ---------------- EdgeConv: P=relu(u[dst]+v[src]); H2=P@W2+b2; segment-max ----------------
// 64 edges/block. W2 B-frags direct from global (L2-resident); single in-loop sync.
__global__ __launch_bounds__(256, 4) void k_edgeconv2(const float* __restrict__ uv,
                                                      const int* __restrict__ csr_src,
                                                      const int* __restrict__ csr_dst,
                                                      const unsigned short* __restrict__ w2Th,
                                                      const unsigned short* __restrict__ w2Tl,
                                                      const float* __restrict__ b2,
                                                      float* __restrict__ x0, int E) {
  __shared__ __align__(16) char smem[34816];
  unsigned short (*Ph)[136] = (unsigned short(*)[136])smem;            // 17408 B
  unsigned short (*Pl)[136] = (unsigned short(*)[136])(smem + 17408);  // 17408 B
  float (*H2)[132] = (float(*)[132])smem;                              // alias, 33792 B
  __shared__ int sSrc[64], sDst[64];

  const int tid = threadIdx.x;
  const int e0 = blockIdx.x * 64;
  const int w = tid >> 6, lane = tid & 63, quad = lane >> 4, lr = lane & 15;
  if (tid < 64) {
    int e = e0 + tid;
    sSrc[tid] = (e < E) ? csr_src[e] : -1;
    sDst[tid] = (e < E) ? csr_dst[e] : -1;
  }
  __syncthreads();
  // build P (64 x 128) split bf16
  #pragma unroll
  for (int c = tid; c < 1024; c += 256) {
    int r = c >> 4;
    int kq = (c & 15) * 8;
    float pv[8];
    int sn = sSrc[r], dn = sDst[r];
    if (sn >= 0) {
      float4 u0 = *(const float4*)&uv[(size_t)dn * 256 + kq];
      float4 u1 = *(const float4*)&uv[(size_t)dn * 256 + kq + 4];
      float4 v0 = *(const float4*)&uv[(size_t)sn * 256 + 128 + kq];
      float4 v1 = *(const float4*)&uv[(size_t)sn * 256 + 128 + kq + 4];
      pv[0] = fmaxf(u0.x + v0.x, 0.f); pv[1] = fmaxf(u0.y + v0.y, 0.f);
      pv[2] = fmaxf(u0.z + v0.z, 0.f); pv[3] = fmaxf(u0.w + v0.w, 0.f);
      pv[4] = fmaxf(u1.x + v1.x, 0.f); pv[5] = fmaxf(u1.y + v1.y, 0.f);
      pv[6] = fmaxf(u1.z + v1.z, 0.f); pv[7] = fmaxf(u1.w + v1.w, 0.f);
    } else {
      #pragma unroll
      for (int i = 0; i < 8; ++i) pv[i] = 0.f;
    }
    short8 h8, l8;
    #pragma unroll
    for (int i = 0; i < 8; ++i) {
      unsigned short h = bf16_rn(pv[i]);
      h8[i] = (short)h;
      l8[i] = (short)bf16_rn(pv[i] - bf16_to_f(h));
    }
    *(short8*)&Ph[r][kq] = h8;
    *(short8*)&Pl[r][kq] = l8;
  }
  __syncthreads();
  float4v zero4 = {0.f, 0.f, 0.f, 0.f};
  float4v acc[4][2];
  #pragma unroll
  for (int mt = 0; mt < 4; ++mt)
    #pragma unroll
    for (int nt = 0; nt < 2; ++nt) acc[mt][nt] = zero4;

  #pragma unroll
  for (int k0 = 0; k0 < 128; k0 += 32) {
    short8 ah[4], alo[4], bh[2], blo[2];
    #pragma unroll
    for (int nt = 0; nt < 2; ++nt) {
      int n = w * 32 + nt * 16 + lr;
      bh[nt]  = *(const short8*)&w2Th[(size_t)n * 128 + k0 + quad * 8];
      blo[nt] = *(const short8*)&w2Tl[(size_t)n * 128 + k0 + quad * 8];
    }
    #pragma unroll
    for (int mt = 0; mt < 4; ++mt) {
      ah[mt]  = *(short8*)&Ph[mt * 16 + lr][k0 + quad * 8];
      alo[mt] = *(short8*)&Pl[mt * 16 + lr][k0 + quad * 8];
    }
    #pragma unroll
    for (int mt = 0; mt < 4; ++mt)
      #pragma unroll
      for (int nt = 0; nt < 2; ++nt) {
        acc[mt][nt] = __builtin_amdgcn_mfma_f32_16x16x32_bf16(ah[mt], bh[nt], acc[mt][nt], 0, 0, 0);
        acc[mt][nt] = __builtin_amdgcn_mfma_f32_16x16x32_bf16(alo[mt], bh[nt], acc[mt][nt], 0, 0, 0);
        acc[mt][nt] = __builtin_amdgcn_mfma_f32_16x16x32_bf16(ah[mt], blo[nt], acc[mt][nt], 0, 0, 0);
      }
  }
  __syncthreads();  // P dead; reuse as H2
  #pragma unroll
  for (int nt = 0; nt < 2; ++nt) {
    int n = w * 32 + nt * 16 + lr;
    float bv = b2[n];
    #pragma unroll
    for (int mt = 0; mt < 4; ++mt) {
      #pragma unroll
      for (int r = 0; r < 4; ++r) {
        int row = mt * 16 + quad * 4 + r;
        H2[row][n] = acc[mt][nt][r] + bv;
      }
    }
  }
  __syncthreads();
  if (tid < 128) {
    int col = tid;
    int prev = sDst[0];
    float rmax = H2[0][col];
    for (int r = 1; r < 64; ++r) {
      int d = sDst[r];
      float v = H2[r][col];
      if (d == prev) {
        rmax = fmaxf(rmax, v);
      } else {
        if (prev >= 0) atomicMaxF(&x0[(size_t)prev * 128 + col], rmax);
        prev = d;
        rmax = v;
      }
    }
    if (prev >= 0) atomicMaxF(&x0[(size_t)prev * 128 + col], rmax);
  }
}

__global__ __launch_bounds__(256) void k_finalize(float* p, int n) {
  int i = blockIdx.x * 256 + threadIdx.x;
  if (i < n) {
    float v = p[i];
    if (v == -INFINITY) p[i] = 0.f;
  }
}

// ---------------- GAT segment softmax + aggregation, one wave per node ----------------
__global__ __launch_bounds__(256) void k_gat_agg(const float* __restrict__ Hf,
                                                 const float* __restrict__ al,
                                                 const int* __restrict__ rs,
                                                 const int* __restrict__ csr_src,
                                                 const float* __restrict__ bias,
                                                 const float* __restrict__ res,
                                                 float* __restrict__ out, int N) {
  int wave = threadIdx.x >> 6, lane = threadIdx.x & 63;
  int i = blockIdx.x * 4 + wave;
  if (i >= N) return;
  int beg = rs[i], end = rs[i + 1];
  int deg = end - beg;
  float4 me = *(const float4*)&al[i * 4];
  float ad0 = me.z, ad1 = me.w;
  float sl0 = leaky(me.x + ad0);
  float sl1 = leaky(me.y + ad1);
  const int c = lane << 2;
  const int hsel = lane >> 5;
  float a0, a1, a2, a3;

  if (deg <= 64) {
    // ---- lane-parallel logit phase ----
    int s = 0;
    float l0 = -INFINITY, l1 = -INFINITY;
    bool act = lane < deg;
    if (act) {
      s = csr_src[beg + lane];
      float4 a4 = *(const float4*)&al[s * 4];
      l0 = leaky(a4.x + ad0);
      l1 = leaky(a4.y + ad1);
    }
    float m0 = fmaxf(sl0, l0), m1 = fmaxf(sl1, l1);
    #pragma unroll
    for (int o = 32; o; o >>= 1) {
      m0 = fmaxf(m0, __shfl_xor(m0, o));
      m1 = fmaxf(m1, __shfl_xor(m1, o));
    }
    float w0 = act ? __expf(l0 - m0) : 0.f;
    float w1 = act ? __expf(l1 - m1) : 0.f;
    float s0 = w0, s1 = w1;
    #pragma unroll
    for (int o = 32; o; o >>= 1) {
      s0 += __shfl_xor(s0, o);
      s1 += __shfl_xor(s1, o);
    }
    s0 += __expf(sl0 - m0);
    s1 += __expf(sl1 - m1);
    float inv0 = 1.f / (s0 + 1e-16f), inv1 = 1.f / (s1 + 1e-16f);
    float wp0 = w0 * inv0, wp1 = w1 * inv1;
    // ---- gather phase ----
    float wself = hsel ? __expf(sl1 - m1) * inv1 : __expf(sl0 - m0) * inv0;
    float4 hv = *(const float4*)&Hf[(size_t)i * 256 + c];
    a0 = wself * hv.x; a1 = wself * hv.y; a2 = wself * hv.z; a3 = wself * hv.w;
    float b0 = 0.f, b1 = 0.f, b2 = 0.f, b3 = 0.f;
    float c0 = 0.f, c1 = 0.f, c2 = 0.f, c3 = 0.f;
    float d0 = 0.f, d1 = 0.f, d2 = 0.f, d3 = 0.f;
    int j = 0;
    for (; j + 4 <= deg; j += 4) {
      int s_0 = __shfl(s, j);     float wA0 = __shfl(wp0, j);     float wB0 = __shfl(wp1, j);
      int s_1 = __shfl(s, j + 1); float wA1 = __shfl(wp0, j + 1); float wB1 = __shfl(wp1, j + 1);
      int s_2 = __shfl(s, j + 2); float wA2 = __shfl(wp0, j + 2); float wB2 = __shfl(wp1, j + 2);
      int s_3 = __shfl(s, j + 3); float wA3 = __shfl(wp0, j + 3); float wB3 = __shfl(wp1, j + 3);
      float4 h0 = *(const float4*)&Hf[(size_t)s_0 * 256 + c];
      float4 h1 = *(const float4*)&Hf[(size_t)s_1 * 256 + c];
      float4 h2 = *(const float4*)&Hf[(size_t)s_2 * 256 + c];
      float4 h3 = *(const float4*)&Hf[(size_t)s_3 * 256 + c];
      float w_0 = hsel ? wB0 : wA0;
      float w_1 = hsel ? wB1 : wA1;
      float w_2 = hsel ? wB2 : wA2;
      float w_3 = hsel ? wB3 : wA3;
      a0 += w_0 * h0.x; a1 += w_0 * h0.y; a2 += w_0 * h0.z; a3 += w_0 * h0.w;
      b0 += w_1 * h1.x; b1 += w_1 * h1.y; b2 += w_1 * h1.z; b3 += w_1 * h1.w;
      c0 += w_2 * h2.x; c1 += w_2 * h2.y; c2 += w_2 * h2.z; c3 += w_2 * h2.w;
      d0 += w_3 * h3.x; d1 += w_3 * h3.y; d2 += w_3 * h3.z; d3 += w_3 * h3.w;
    }
    for (; j < deg; ++j) {
      int sj = __shfl(s, j);
      float wA = __shfl(wp0, j), wB = __shfl(wp1, j);
      float wj = hsel ? wB : wA;
      float4 h4 = *(const float4*)&Hf[(size_t)sj * 256 + c];
      a0 += wj * h4.x; a1 += wj * h4.y; a2 += wj * h4.z; a3 += wj * h4.w;
    }
    a0 += b0 + c0 + d0; a1 += b1 + c1 + d1;
    a2 += b2 + c2 + d2; a3 += b3 + c3 + d3;
  } else {
    // ---- general path (rare) ----
    float m0 = sl0, m1 = sl1;
    for (int e = beg + lane; e < end; e += 64) {
      int s = csr_src[e];
      m0 = fmaxf(m0, leaky(al[s * 4 + 0] + ad0));
      m1 = fmaxf(m1, leaky(al[s * 4 + 1] + ad1));
    }
    #pragma unroll
    for (int o = 32; o; o >>= 1) {
      m0 = fmaxf(m0, __shfl_xor(m0, o));
      m1 = fmaxf(m1, __shfl_xor(m1, o));
    }
    float s0 = 0.f, s1 = 0.f;
    for (int e = beg + lane; e < end; e += 64) {
      int s = csr_src[e];
      s0 += __expf(leaky(al[s * 4 + 0] + ad0) - m0);
      s1 += __expf(leaky(al[s * 4 + 1] + ad1) - m1);
    }
    #pragma unroll
    for (int o = 32; o; o >>= 1) {
      s0 += __shfl_xor(s0, o);
      s1 += __shfl_xor(s1, o);
    }
    s0 += __expf(sl0 - m0);
    s1 += __expf(sl1 - m1);
    float inv0 = 1.f / (s0 + 1e-16f), inv1 = 1.f / (s1 + 1e-16f);
    float mh = hsel ? m1 : m0;
    float invh = hsel ? inv1 : inv0;
    float adh = hsel ? ad1 : ad0;
    float wself = __expf((hsel ? sl1 : sl0) - mh) * invh;
    float4 hv = *(const float4*)&Hf[(size_t)i * 256 + c];
    a0 = wself * hv.x; a1 = wself * hv.y; a2 = wself * hv.z; a3 = wself * hv.w;
    for (int e = beg; e < end; ++e) {
      int s = csr_src[e];
      float wgt = __expf(leaky(al[s * 4 + hsel] + adh) - mh) * invh;
      float4 h4 = *(const float4*)&Hf[(size_t)s * 256 + c];
      a0 += wgt * h4.x; a1 += wgt * h4.y; a2 += wgt * h4.z; a3 += wgt * h4.w;
    }
  }
  float4 bv = *(const float4*)&bias[c];
  float4 o4;
  o4.x = fmaxf(a0 + bv.x, 0.f);
  o4.y = fmaxf(a1 + bv.y, 0.f);
  o4.z = fmaxf(a2 + bv.z, 0.f);
  o4.w = fmaxf(a3 + bv.w, 0.f);
  if (res) {
    float4 r4 = *(const float4*)&res[(size_t)i * 256 + c];
    o4.x += r4.x; o4.y += r4.y; o4.z += r4.z; o4.w += r4.w;
  }
  *(float4*)&out[(size_t)i * 256 + c] = o4;
}

// ---------------- final projection ----------------
__global__ __launch_bounds__(256) void k_findot(const float* __restrict__ X,
                                                const float* __restrict__ fw,
                                                const float* __restrict__ fb,
                                                float* __restrict__ out, int N) {
  int wave = threadIdx.x >> 6, lane = threadIdx.x & 63;
  int i = blockIdx.x * 4 + wave;
  if (i >= N) return;
  float4 xv = *(const float4*)&X[(size_t)i * 256 + (lane << 2)];
  float4 wv = *(const float4*)&fw[lane << 2];
  float p = xv.x * wv.x + xv.y * wv.y + xv.z * wv.z + xv.w * wv.w;
  #pragma unroll
  for (int o = 32; o; o >>= 1) p += __shfl_xor(p, o);
  if (lane == 0) out[i] = p + fb[0];
}

// ---------------------------------------------------------------------------
extern "C" void kernel_launch(void* const* d_in, const int* in_sizes, int n_in,
                              void* d_out, int out_size, void* d_ws, size_t ws_size,
                              hipStream_t stream) {
  const float* x      = (const float*)d_in[0];
  const int*   ei     = (const int*)d_in[1];
  const float* ec_w1  = (const float*)d_in[3];
  const float* ec_b1  = (const float*)d_in[4];
  const float* ec_w2  = (const float*)d_in[5];
  const float* ec_b2  = (const float*)d_in[6];
  const float* reg_w  = (const float*)d_in[7];
  const float* reg_b  = (const float*)d_in[8];
  const float* fin_w  = (const float*)d_in[9];
  const float* fin_b  = (const float*)d_in[10];
  const float* g1_w   = (const float*)d_in[11];
  const float* g1_as  = (const float*)d_in[12];
  const float* g1_ad  = (const float*)d_in[13];
  const float* g1_b   = (const float*)d_in[14];
  const float* g2_w   = (const float*)d_in[15];
  const float* g2_as  = (const float*)d_in[16];
  const float* g2_ad  = (const float*)d_in[17];
  const float* g2_b   = (const float*)d_in[18];
  const float* g3_w   = (const float*)d_in[19];
  const float* g3_as  = (const float*)d_in[20];
  const float* g3_ad  = (const float*)d_in[21];
  const float* g3_b   = (const float*)d_in[22];
  const float* g4_w   = (const float*)d_in[23];
  const float* g4_as  = (const float*)d_in[24];
  const float* g4_ad  = (const float*)d_in[25];
  const float* g4_b   = (const float*)d_in[26];

  const int N = in_sizes[0] / 128;
  const int E = in_sizes[1] / 2;

  char* base = (char*)d_ws;
  size_t off = 0;
  auto alloc = [&](size_t bytes) -> char* {
    char* p = base + off;
    off += (bytes + 255) & ~(size_t)255;
    return p;
  };
  const size_t szN4 = ((size_t)N * 4 + 255) & ~(size_t)255;
  int*   deg      = (int*)alloc((size_t)N * 4);
  int*   cnt      = (int*)alloc((size_t)N * 4);
  int*   rs       = (int*)alloc((size_t)(N + 1) * 4);
  int*   csr_src  = (int*)alloc((size_t)E * 4);
  int*   csr_dst  = (int*)alloc((size_t)E * 4);
  float* bias_cat = (float*)alloc(256 * 4);
  unsigned short* bcatTh = (unsigned short*)alloc(256 * 128 * 2);
  unsigned short* bcatTl = (unsigned short*)alloc(256 * 128 * 2);
  unsigned short* w2Th   = (unsigned short*)alloc(128 * 128 * 2);
  unsigned short* w2Tl   = (unsigned short*)alloc(128 * 128 * 2);
  unsigned short* g1Th   = (unsigned short*)alloc(256 * 128 * 2);
  unsigned short* g1Tl   = (unsigned short*)alloc(256 * 128 * 2);
  unsigned short* g2Th   = (unsigned short*)alloc(256 * 256 * 2);
  unsigned short* g2Tl   = (unsigned short*)alloc(256 * 256 * 2);
  unsigned short* g3Th   = (unsigned short*)alloc(256 * 256 * 2);
  unsigned short* g3Tl   = (unsigned short*)alloc(256 * 256 * 2);
  unsigned short* g4Th   = (unsigned short*)alloc(256 * 256 * 2);
  unsigned short* g4Tl   = (unsigned short*)alloc(256 * 256 * 2);
  unsigned short* regTh  = (unsigned short*)alloc(256 * 256 * 2);
  unsigned short* regTl  = (unsigned short*)alloc(256 * 256 * 2);
  float* uv = (float*)alloc((size_t)N * 256 * 4);
  float* x0 = (float*)alloc((size_t)N * 128 * 4);
  float* X1 = (float*)alloc((size_t)N * 256 * 4);
  float* X2 = (float*)alloc((size_t)N * 256 * 4);
  float* al = (float*)alloc((size_t)N * 4 * 4);
  (void)ws_size; (void)n_in; (void)out_size;

  const int nodeWaveBlocks = (N + 3) / 4;
  const dim3 gemmGrid((N + 63) / 64, 2);

  // --- weight prep (one launch for all transposes/splits) ---
  SplitJobs jobs;
  jobs.j[0] = {ec_w2, nullptr, w2Th, w2Tl, nullptr, 128, 128, 7, 0};
  jobs.j[1] = {g1_w,  nullptr, g1Th, g1Tl, nullptr, 128, 256, 7, 0};
  jobs.j[2] = {g2_w,  nullptr, g2Th, g2Tl, nullptr, 256, 256, 8, 0};
  jobs.j[3] = {g3_w,  nullptr, g3Th, g3Tl, nullptr, 256, 256, 8, 0};
  jobs.j[4] = {g4_w,  nullptr, g4Th, g4Tl, nullptr, 256, 256, 8, 0};
  jobs.j[5] = {reg_w, nullptr, regTh, regTl, nullptr, 256, 256, 8, 0};
  jobs.j[6] = {ec_w1, ec_b1, bcatTh, bcatTl, bias_cat, 128, 256, 7, 1};
  k_prep_all<<<dim3(256, 7), 256, 0, stream>>>(jobs);

  // --- CSR build ---
  hipMemsetAsync(deg, 0, 2 * szN4, stream);  // deg + cnt are adjacent
  k_hist<<<(E + 255) / 256, 256, 0, stream>>>(ei, deg, E);
  k_scan<<<1, 1024, 0, stream>>>(deg, rs, N);
  k_scatter<<<(E + 255) / 256, 256, 0, stream>>>(ei, rs, cnt, csr_src, csr_dst, E);

  // --- EdgeConv ---
  k_gemm_mfma<<<gemmGrid, 256, 0, stream>>>(x, bcatTh, bcatTl, bias_cat, uv, N, 128,
                                            nullptr, nullptr, nullptr);
  k_fill_f32<<<(N * 128 + 255) / 256, 256, 0, stream>>>(x0, -INFINITY, N * 128);
  k_edgeconv2<<<(E + 63) / 64, 256, 0, stream>>>(uv, csr_src, csr_dst, w2Th, w2Tl, ec_b2, x0, E);
  k_finalize<<<(N * 128 + 255) / 256, 256, 0, stream>>>(x0, N * 128);

  // --- GAT1: X1 = relu(gat(x0)) ---
  k_gemm_mfma<<<gemmGrid, 256, 0, stream>>>(x0, g1Th, g1Tl, nullptr, uv, N, 128,
                                            g1_as, g1_ad, al);
  k_gat_agg<<<nodeWaveBlocks, 256, 0, stream>>>(uv, al, rs, csr_src, g1_b, nullptr, X1, N);

  // --- GAT2: X2 = relu(gat(X1)) + X1 ---
  k_gemm_mfma<<<gemmGrid, 256, 0, stream>>>(X1, g2Th, g2Tl, nullptr, uv, N, 256,
                                            g2_as, g2_ad, al);
  k_gat_agg<<<nodeWaveBlocks, 256, 0, stream>>>(uv, al, rs, csr_src, g2_b, X1, X2, N);

  // --- reg: X1 = X2 @ reg_w + reg_b ---
  k_gemm_mfma<<<gemmGrid, 256, 0, stream>>>(X2, regTh, regTl, reg_b, X1, N, 256,
                                            nullptr, nullptr, nullptr);

  // --- GAT3: X2 = relu(gat(X1)) + X1 ---
  k_gemm_mfma<<<gemmGrid, 256, 0, stream>>>(X1, g3Th, g3Tl, nullptr, uv, N, 256,
                                            g3_as, g3_ad, al);
  k_gat_agg<<<nodeWaveBlocks, 256, 0, stream>>>(uv, al, rs, csr_src, g3_b, X1, X2, N);

  // --- GAT4: X1 = relu(gat(X2)) ---
  k_gemm_mfma<<<gemmGrid, 256, 0, stream>>>(X2, g4Th, g4Tl, nullptr, uv, N, 256,
                                            g4_as, g4_ad, al);
  k_gat_agg<<<nodeWaveBlocks, 256, 0, stream>>>(uv, al, rs, csr_src, g4_b, nullptr, X1, N);

  // --- final linear ---
  k_findot<<<nodeWaveBlocks, 256, 0, stream>>>(X1, fin_w, fin_b, (float*)d_out, N);
}